// Round 3
// baseline (257.778 us; speedup 1.0000x reference)
//
#include <hip/hip_runtime.h>

// VectorQuantizer gfx950 R7: R6 structure at 2 blocks/CU (the clean occupancy
// experiment). R4/R6 identical times with totally different K-loops proved the
// K-loop chain is not the limiter; everything is latency-bound at 1 block/CU,
// 2 waves/SIMD, with phases serialized by the block's barrier. R7 keeps R6's
// algorithm but MTILE 512->256, grid 512 -> 2 blocks/CU (16 waves/CU, 4/SIMD).
// Per-CU totals (MFMA, LDS reads, reduce ops, HBM bytes) are UNCHANGED vs R6 --
// only parallelism rises, and co-resident blocks at different phases overlap
// staging stalls with MFMA and stores. LDS 36 KB/block; no A double-buffer
// (4 waves/SIMD hides the 4 ds_reads/stage); __launch_bounds__(512,4) pins
// 4 waves/SIMD.
//  - Wave w holds B-fragments for codes [128w,128w+128) in 64 VGPRs + cc in 8.
//  - LDS holds the x-tile as bf16(-2x), 256 rows x stride 68 (~34 KB).
//  - 8 stages: in stage s, wave w computes row-group (w+s)&7 (32 rows) vs its
//    128 codes: 32 register-only MFMAs + packed-key v_min.
//  - Per-row argmin merged across waves via ds_atomic_min on keys[256].
// dist2[n,k] = ||x||^2 - 2 x.e_k + ||e_k||^2 ; argmin invariant to ||x||^2.
// MFMA C-init cc = 0.5 + ||e_k||^2 => output s in [0.375,0.625] > 0 => IEEE
// bits order-monotonic. key = (bits(s) & ~1023) | code; argmin = v_min_u32.

typedef __attribute__((ext_vector_type(8))) short short8;
typedef __attribute__((ext_vector_type(4))) float f32x4;

#define VQ_D 64
#define MTILE 256
#define NTH 512
#define AS 68  // ushorts per x row in LDS (64 data + 4 pad); 0 measured conflicts

__device__ inline unsigned short f2bf(float f) {
  union { float f; unsigned u; } v; v.f = f;
  unsigned r = v.u + 0x7FFFu + ((v.u >> 16) & 1u);  // RNE
  return (unsigned short)(r >> 16);
}

// Prep: one wave per codebook row. c2b[k] = 0.5 + ||e_k||^2 ; codebook -> bf16.
// Also zeroes the sse accumulator and completion counter.
__global__ __launch_bounds__(256) void vq_prep(const float* __restrict__ cb,
                                               float* __restrict__ c2b,
                                               unsigned short* __restrict__ cbb,
                                               float* __restrict__ sse,
                                               unsigned* __restrict__ counter, int K) {
  if (blockIdx.x == 0 && threadIdx.x == 0) { *sse = 0.f; *counter = 0u; }
  int w = (int)((blockIdx.x * 256 + threadIdx.x) >> 6);
  int lane = threadIdx.x & 63;
  if (w >= K) return;
  float v = cb[(size_t)w * VQ_D + lane];
  cbb[(size_t)w * VQ_D + lane] = f2bf(v);
  float s = v * v;
#pragma unroll
  for (int off = 32; off; off >>= 1) s += __shfl_down(s, off);
  if (lane == 0) c2b[w] = s + 0.5f;
}

__global__ __launch_bounds__(NTH, 4) void vq_main(
    const float* __restrict__ x, const float* __restrict__ cb,
    const float* __restrict__ c2b, const unsigned short* __restrict__ cbb,
    float* __restrict__ out, float* __restrict__ sse_out,
    unsigned* __restrict__ counter, int nblocks) {
  __shared__ unsigned short xb[MTILE * AS];  // 34816 B
  __shared__ unsigned keys[MTILE];           // 1024 B
  __shared__ float redbuf[8];

  const int tid = threadIdx.x;
  const int wave = tid >> 6;
  const int lane = tid & 63;
  const int quad = lane >> 4;
  const int col = lane & 15;
  const long blockRow0 = (long)blockIdx.x * MTILE;

  // ---- This wave's resident codebook slice: 128 codes in registers.
  // Lane(quad,col) holds code (ci*16+col), dims [ks*32+quad*8, +8).
  short8 B[8][2];
  float cc[8];
  const int code0 = wave * 128;
#pragma unroll
  for (int ci = 0; ci < 8; ++ci) {
    const unsigned short* bp = cbb + (size_t)(code0 + ci * 16 + col) * VQ_D + quad * 8;
    B[ci][0] = *(const short8*)bp;
    B[ci][1] = *(const short8*)(bp + 32);
    cc[ci] = c2b[code0 + ci * 16 + col];
  }

  if (tid < MTILE) keys[tid] = 0xFFFFFFFFu;

  // ---- Stage x tile as bf16(-2x) into LDS. 2048 short8 chunks / 512 thr = 4 it.
#pragma unroll
  for (int i = 0; i < 4; ++i) {
    int id = i * NTH + tid;
    int row = id >> 3;
    int piece = id & 7;
    const f32x4* xp = (const f32x4*)(x + (blockRow0 + row) * VQ_D + piece * 8);
    f32x4 lo = xp[0];
    f32x4 hi = xp[1];
    short8 a;
    a[0] = (short)f2bf(-2.f * lo[0]); a[1] = (short)f2bf(-2.f * lo[1]);
    a[2] = (short)f2bf(-2.f * lo[2]); a[3] = (short)f2bf(-2.f * lo[3]);
    a[4] = (short)f2bf(-2.f * hi[0]); a[5] = (short)f2bf(-2.f * hi[1]);
    a[6] = (short)f2bf(-2.f * hi[2]); a[7] = (short)f2bf(-2.f * hi[3]);
    *(short8*)(xb + row * AS + piece * 8) = a;
  }
  __syncthreads();  // x tile staged + keys initialized; only barrier before epilogue

  // ---- 8 stages: register-resident MFMA block; A-frags 4 ds_reads/stage.
  for (int s = 0; s < 8; ++s) {
    const int g = (wave + s) & 7;

    short8 Ac[2][2];
#pragma unroll
    for (int mi = 0; mi < 2; ++mi)
#pragma unroll
      for (int ks = 0; ks < 2; ++ks)
        Ac[mi][ks] = *(const short8*)(xb + (g * 32 + mi * 16 + col) * AS + ks * 32 + quad * 8);

    unsigned bk[2][4];
#pragma unroll
    for (int mi = 0; mi < 2; ++mi)
#pragma unroll
      for (int r = 0; r < 4; ++r) bk[mi][r] = 0xFFFFFFFFu;

#pragma unroll
    for (int mi = 0; mi < 2; ++mi) {
#pragma unroll
      for (int ci = 0; ci < 8; ++ci) {
        f32x4 a = {cc[ci], cc[ci], cc[ci], cc[ci]};
        a = __builtin_amdgcn_mfma_f32_16x16x32_bf16(Ac[mi][0], B[ci][0], a, 0, 0, 0);
        a = __builtin_amdgcn_mfma_f32_16x16x32_bf16(Ac[mi][1], B[ci][1], a, 0, 0, 0);
        const unsigned code = (unsigned)(code0 + ci * 16 + col);
#pragma unroll
        for (int r = 0; r < 4; ++r)
          bk[mi][r] = min(bk[mi][r], (__float_as_uint(a[r]) & 0xFFFFFC00u) | code);
      }
    }

    // Reduce keys across the 16 columns of each quad group, then merge by row.
#pragma unroll
    for (int off = 1; off < 16; off <<= 1) {
#pragma unroll
      for (int mi = 0; mi < 2; ++mi)
#pragma unroll
        for (int r = 0; r < 4; ++r) {
          unsigned o = (unsigned)__shfl_xor((int)bk[mi][r], off);
          bk[mi][r] = min(bk[mi][r], o);
        }
    }
    if (col == 0) {
#pragma unroll
      for (int mi = 0; mi < 2; ++mi)
#pragma unroll
        for (int r = 0; r < 4; ++r)
          atomicMin(&keys[g * 32 + mi * 16 + quad * 4 + r], bk[mi][r]);
    }
  }
  __syncthreads();

  // ---- Gather quantized rows in exact fp32 + SSE for the loss. Coalesced float4.
  float sse = 0.f;
  const f32x4* cb4 = (const f32x4*)cb;
  const f32x4* x4 = (const f32x4*)x;
  f32x4* out4 = (f32x4*)out;
#pragma unroll
  for (int i = 0; i < 8; ++i) {
    int f = i * NTH + tid;  // float4 index within the 256x16 tile
    int row_l = f >> 4;
    int d4 = f & 15;
    int idx = (int)(keys[row_l] & 1023u);
    f32x4 cv = cb4[(size_t)idx * 16 + d4];
    long gi = (blockRow0 + row_l) * 16 + d4;
    f32x4 xv = x4[gi];
    out4[gi] = cv;
    f32x4 dv = cv - xv;
    sse += dv[0] * dv[0] + dv[1] * dv[1] + dv[2] * dv[2] + dv[3] * dv[3];
  }
#pragma unroll
  for (int off = 32; off; off >>= 1) sse += __shfl_down(sse, off);
  if (lane == 0) redbuf[wave] = sse;
  __syncthreads();

  if (tid == 0) {
    float s = 0.f;
#pragma unroll
    for (int w = 0; w < 8; ++w) s += redbuf[w];
    atomicAdd(sse_out, s);
    __threadfence();
    unsigned old = atomicAdd(counter, 1u);
    if (old == (unsigned)(nblocks - 1)) {
      float tot = atomicAdd(sse_out, 0.f);
      long nelem = (long)nblocks * MTILE * VQ_D;
      out[nelem] = 1.25f * tot / (float)nelem;
    }
  }
}

extern "C" void kernel_launch(void* const* d_in, const int* in_sizes, int n_in,
                              void* d_out, int out_size, void* d_ws, size_t ws_size,
                              hipStream_t stream) {
  const float* x = (const float*)d_in[0];
  const float* cb = (const float*)d_in[1];
  float* out = (float*)d_out;

  const long n_elem = (long)in_sizes[0];   // 8388608
  const int nrows = (int)(n_elem / VQ_D);  // 131072
  const int K = in_sizes[1] / VQ_D;        // 1024
  const int nblocks = nrows / MTILE;       // 512

  char* ws = (char*)d_ws;
  float* sse = (float*)ws;                             // 4 B
  unsigned* counter = (unsigned*)(ws + 64);            // 4 B
  float* c2b = (float*)(ws + 256);                     // 4 KB
  unsigned short* cbb = (unsigned short*)(ws + 8192);  // 128 KB bf16 codebook

  vq_prep<<<dim3((K * 64 + 255) / 256), dim3(256), 0, stream>>>(cb, c2b, cbb, sse, counter, K);
  vq_main<<<dim3(nblocks), dim3(NTH), 0, stream>>>(x, cb, c2b, cbb, out, sse, counter, nblocks);
}

// Round 4
// 133.283 us; speedup vs baseline: 1.9341x; 1.9341x over previous
//
#include <hip/hip_runtime.h>

// VectorQuantizer gfx950 R8: R7 structure with the register cap fixed.
// R7 post-mortem: __launch_bounds__(512,4) acted as CUDA-style minBlocks=4
// -> 64-VGPR cap -> the 64-VGPR register-resident codebook spilled to scratch
// -> FETCH 32->447 MB, 187 us. Fix: plain __launch_bounds__(512); body needs
// ~116 VGPR < 128, so 2 blocks/CU (16 waves/CU, 4 waves/SIMD) fit by VGPR
// (4x~116 <= 512/SIMD) and LDS (2x36 KB <= 160 KB). Per-CU work totals equal
// R6; only parallelism rises, and co-resident blocks at different phases
// overlap staging stalls with MFMA and epilogue stores.
//  - Wave w holds B-fragments for codes [128w,128w+128) in 64 VGPRs + cc in 8.
//  - LDS holds the x-tile as bf16(-2x), 256 rows x stride 68 (~34 KB).
//  - 8 stages: in stage s, wave w computes row-group (w+s)&7 (32 rows) vs its
//    128 codes: 32 register-only MFMAs + packed-key v_min.
//  - Per-row argmin merged across waves via ds_atomic_min on keys[256].
// dist2[n,k] = ||x||^2 - 2 x.e_k + ||e_k||^2 ; argmin invariant to ||x||^2.
// MFMA C-init cc = 0.5 + ||e_k||^2 => output s in [0.375,0.625] > 0 => IEEE
// bits order-monotonic. key = (bits(s) & ~1023) | code; argmin = v_min_u32.

typedef __attribute__((ext_vector_type(8))) short short8;
typedef __attribute__((ext_vector_type(4))) float f32x4;

#define VQ_D 64
#define MTILE 256
#define NTH 512
#define AS 68  // ushorts per x row in LDS (64 data + 4 pad); 0 measured conflicts

__device__ inline unsigned short f2bf(float f) {
  union { float f; unsigned u; } v; v.f = f;
  unsigned r = v.u + 0x7FFFu + ((v.u >> 16) & 1u);  // RNE
  return (unsigned short)(r >> 16);
}

// Prep: one wave per codebook row. c2b[k] = 0.5 + ||e_k||^2 ; codebook -> bf16.
// Also zeroes the sse accumulator and completion counter.
__global__ __launch_bounds__(256) void vq_prep(const float* __restrict__ cb,
                                               float* __restrict__ c2b,
                                               unsigned short* __restrict__ cbb,
                                               float* __restrict__ sse,
                                               unsigned* __restrict__ counter, int K) {
  if (blockIdx.x == 0 && threadIdx.x == 0) { *sse = 0.f; *counter = 0u; }
  int w = (int)((blockIdx.x * 256 + threadIdx.x) >> 6);
  int lane = threadIdx.x & 63;
  if (w >= K) return;
  float v = cb[(size_t)w * VQ_D + lane];
  cbb[(size_t)w * VQ_D + lane] = f2bf(v);
  float s = v * v;
#pragma unroll
  for (int off = 32; off; off >>= 1) s += __shfl_down(s, off);
  if (lane == 0) c2b[w] = s + 0.5f;
}

__global__ __launch_bounds__(NTH) void vq_main(
    const float* __restrict__ x, const float* __restrict__ cb,
    const float* __restrict__ c2b, const unsigned short* __restrict__ cbb,
    float* __restrict__ out, float* __restrict__ sse_out,
    unsigned* __restrict__ counter, int nblocks) {
  __shared__ unsigned short xb[MTILE * AS];  // 34816 B
  __shared__ unsigned keys[MTILE];           // 1024 B
  __shared__ float redbuf[8];

  const int tid = threadIdx.x;
  const int wave = tid >> 6;
  const int lane = tid & 63;
  const int quad = lane >> 4;
  const int col = lane & 15;
  const long blockRow0 = (long)blockIdx.x * MTILE;

  // ---- This wave's resident codebook slice: 128 codes in registers.
  // Lane(quad,col) holds code (ci*16+col), dims [ks*32+quad*8, +8).
  short8 B[8][2];
  float cc[8];
  const int code0 = wave * 128;
#pragma unroll
  for (int ci = 0; ci < 8; ++ci) {
    const unsigned short* bp = cbb + (size_t)(code0 + ci * 16 + col) * VQ_D + quad * 8;
    B[ci][0] = *(const short8*)bp;
    B[ci][1] = *(const short8*)(bp + 32);
    cc[ci] = c2b[code0 + ci * 16 + col];
  }

  if (tid < MTILE) keys[tid] = 0xFFFFFFFFu;

  // ---- Stage x tile as bf16(-2x) into LDS. 2048 short8 chunks / 512 thr = 4 it.
#pragma unroll
  for (int i = 0; i < 4; ++i) {
    int id = i * NTH + tid;
    int row = id >> 3;
    int piece = id & 7;
    const f32x4* xp = (const f32x4*)(x + (blockRow0 + row) * VQ_D + piece * 8);
    f32x4 lo = xp[0];
    f32x4 hi = xp[1];
    short8 a;
    a[0] = (short)f2bf(-2.f * lo[0]); a[1] = (short)f2bf(-2.f * lo[1]);
    a[2] = (short)f2bf(-2.f * lo[2]); a[3] = (short)f2bf(-2.f * lo[3]);
    a[4] = (short)f2bf(-2.f * hi[0]); a[5] = (short)f2bf(-2.f * hi[1]);
    a[6] = (short)f2bf(-2.f * hi[2]); a[7] = (short)f2bf(-2.f * hi[3]);
    *(short8*)(xb + row * AS + piece * 8) = a;
  }
  __syncthreads();  // x tile staged + keys initialized; only barrier before epilogue

  // ---- 8 stages: register-resident MFMA block; A-frags 4 ds_reads/stage.
  for (int s = 0; s < 8; ++s) {
    const int g = (wave + s) & 7;

    short8 Ac[2][2];
#pragma unroll
    for (int mi = 0; mi < 2; ++mi)
#pragma unroll
      for (int ks = 0; ks < 2; ++ks)
        Ac[mi][ks] = *(const short8*)(xb + (g * 32 + mi * 16 + col) * AS + ks * 32 + quad * 8);

    unsigned bk[2][4];
#pragma unroll
    for (int mi = 0; mi < 2; ++mi)
#pragma unroll
      for (int r = 0; r < 4; ++r) bk[mi][r] = 0xFFFFFFFFu;

#pragma unroll
    for (int mi = 0; mi < 2; ++mi) {
#pragma unroll
      for (int ci = 0; ci < 8; ++ci) {
        f32x4 a = {cc[ci], cc[ci], cc[ci], cc[ci]};
        a = __builtin_amdgcn_mfma_f32_16x16x32_bf16(Ac[mi][0], B[ci][0], a, 0, 0, 0);
        a = __builtin_amdgcn_mfma_f32_16x16x32_bf16(Ac[mi][1], B[ci][1], a, 0, 0, 0);
        const unsigned code = (unsigned)(code0 + ci * 16 + col);
#pragma unroll
        for (int r = 0; r < 4; ++r)
          bk[mi][r] = min(bk[mi][r], (__float_as_uint(a[r]) & 0xFFFFFC00u) | code);
      }
    }

    // Reduce keys across the 16 columns of each quad group, then merge by row.
#pragma unroll
    for (int off = 1; off < 16; off <<= 1) {
#pragma unroll
      for (int mi = 0; mi < 2; ++mi)
#pragma unroll
        for (int r = 0; r < 4; ++r) {
          unsigned o = (unsigned)__shfl_xor((int)bk[mi][r], off);
          bk[mi][r] = min(bk[mi][r], o);
        }
    }
    if (col == 0) {
#pragma unroll
      for (int mi = 0; mi < 2; ++mi)
#pragma unroll
        for (int r = 0; r < 4; ++r)
          atomicMin(&keys[g * 32 + mi * 16 + quad * 4 + r], bk[mi][r]);
    }
  }
  __syncthreads();

  // ---- Gather quantized rows in exact fp32 + SSE for the loss. Coalesced float4.
  float sse = 0.f;
  const f32x4* cb4 = (const f32x4*)cb;
  const f32x4* x4 = (const f32x4*)x;
  f32x4* out4 = (f32x4*)out;
#pragma unroll
  for (int i = 0; i < 8; ++i) {
    int f = i * NTH + tid;  // float4 index within the 256x16 tile
    int row_l = f >> 4;
    int d4 = f & 15;
    int idx = (int)(keys[row_l] & 1023u);
    f32x4 cv = cb4[(size_t)idx * 16 + d4];
    long gi = (blockRow0 + row_l) * 16 + d4;
    f32x4 xv = x4[gi];
    out4[gi] = cv;
    f32x4 dv = cv - xv;
    sse += dv[0] * dv[0] + dv[1] * dv[1] + dv[2] * dv[2] + dv[3] * dv[3];
  }
#pragma unroll
  for (int off = 32; off; off >>= 1) sse += __shfl_down(sse, off);
  if (lane == 0) redbuf[wave] = sse;
  __syncthreads();

  if (tid == 0) {
    float s = 0.f;
#pragma unroll
    for (int w = 0; w < 8; ++w) s += redbuf[w];
    atomicAdd(sse_out, s);
    __threadfence();
    unsigned old = atomicAdd(counter, 1u);
    if (old == (unsigned)(nblocks - 1)) {
      float tot = atomicAdd(sse_out, 0.f);
      long nelem = (long)nblocks * MTILE * VQ_D;
      out[nelem] = 1.25f * tot / (float)nelem;
    }
  }
}

extern "C" void kernel_launch(void* const* d_in, const int* in_sizes, int n_in,
                              void* d_out, int out_size, void* d_ws, size_t ws_size,
                              hipStream_t stream) {
  const float* x = (const float*)d_in[0];
  const float* cb = (const float*)d_in[1];
  float* out = (float*)d_out;

  const long n_elem = (long)in_sizes[0];   // 8388608
  const int nrows = (int)(n_elem / VQ_D);  // 131072
  const int K = in_sizes[1] / VQ_D;        // 1024
  const int nblocks = nrows / MTILE;       // 512

  char* ws = (char*)d_ws;
  float* sse = (float*)ws;                             // 4 B
  unsigned* counter = (unsigned*)(ws + 64);            // 4 B
  float* c2b = (float*)(ws + 256);                     // 4 KB
  unsigned short* cbb = (unsigned short*)(ws + 8192);  // 128 KB bf16 codebook

  vq_prep<<<dim3((K * 64 + 255) / 256), dim3(256), 0, stream>>>(cb, c2b, cbb, sse, counter, K);
  vq_main<<<dim3(nblocks), dim3(NTH), 0, stream>>>(x, cb, c2b, cbb, out, sse, counter, nblocks);
}

// Round 5
// 132.186 us; speedup vs baseline: 1.9501x; 1.0083x over previous
//
#include <hip/hip_runtime.h>

// VectorQuantizer gfx950 R9: R4 base (full padded bf16 codebook in LDS, one
// barrier, barrier-free 64-iter MFMA K-loop, packed u32 argmin keys) with the
// VMEM instruction stream cut down. Clock-derived analysis (MfmaUtil ~10% with
// 5.1k cyc of MFMA/CU => T~50k cyc @ ~800 MHz effective) shows ~35k stall
// cycles shared by all prior structures; the common term is ~640 wave-level
// VMEM instructions/CU at ~50-60 cyc each. R9:
//  - Epilogue gathers quantized rows from the LDS bf16 codebook (ds_read_b64 +
//    cvt) instead of global fp32 (-128 VMEM/CU). Output = bf16-rounded codebook
//    rows: |err| <= 2^-9/1024 ~ 2e-6 << 1.95e-3 tolerance (codebook bound
//    1/1024); loss shift ~5e-6.
//  - Codebook staged via global_load_lds width=16 (linear 139 KB copy of the
//    PADDED layout prep now writes): no VGPR round-trip, no staging VALU, deep
//    vmcnt overlap with the A-frag loads issued right after.
// dist2[n,k] = ||x||^2 - 2 x.e_k + ||e_k||^2 ; argmin invariant to ||x||^2.
// A-fragments hold bf16(-2x) (exact pow2 scale); MFMA C-operand initialized to
// cc = 0.5 + ||e_k||^2 so the MFMA output IS the score s in [0.375,0.625] (>0
// => IEEE bits order-monotonic). key = (bits(s) & ~1023) | code; argmin =
// v_min_u32. LDS row stride 68 ushorts. Grid = 256 blocks of 512 = 1 block/CU.

typedef __attribute__((ext_vector_type(8))) short short8;
typedef __attribute__((ext_vector_type(4))) float f32x4;

#define VQ_D 64
#define MTILE 512   // rows per block (8 waves x 64 rows)
#define NTH 512
#define CSTRIDE 68  // ushorts per code row (64 data + 4 pad), padded in GLOBAL too

__device__ inline unsigned short f2bf(float f) {
  union { float f; unsigned u; } v; v.f = f;
  unsigned r = v.u + 0x7FFFu + ((v.u >> 16) & 1u);  // RNE
  return (unsigned short)(r >> 16);
}

// Prep: one wave per codebook row. c2b[k] = 0.5 + ||e_k||^2 ; codebook -> bf16
// in the PADDED stride-68 layout (zeroed pad) so vq_main can do a linear
// global_load_lds copy. Also zeroes the sse accumulator and completion counter.
__global__ __launch_bounds__(256) void vq_prep(const float* __restrict__ cb,
                                               float* __restrict__ c2b,
                                               unsigned short* __restrict__ cbb,
                                               float* __restrict__ sse,
                                               unsigned* __restrict__ counter, int K) {
  if (blockIdx.x == 0 && threadIdx.x == 0) { *sse = 0.f; *counter = 0u; }
  int w = (int)((blockIdx.x * 256 + threadIdx.x) >> 6);
  int lane = threadIdx.x & 63;
  if (w >= K) return;
  float v = cb[(size_t)w * VQ_D + lane];
  cbb[(size_t)w * CSTRIDE + lane] = f2bf(v);
  if (lane < CSTRIDE - VQ_D) cbb[(size_t)w * CSTRIDE + VQ_D + lane] = 0;
  float s = v * v;
#pragma unroll
  for (int off = 32; off; off >>= 1) s += __shfl_down(s, off);
  if (lane == 0) c2b[w] = s + 0.5f;
}

__global__ __launch_bounds__(NTH) void vq_main(
    const float* __restrict__ x, const float* __restrict__ cb,
    const float* __restrict__ c2b, const unsigned short* __restrict__ cbb,
    float* __restrict__ out, float* __restrict__ sse_out,
    unsigned* __restrict__ counter, int nblocks) {
  __shared__ unsigned short cbs[1024 * CSTRIDE];  // 139264 B
  __shared__ float c2s[1024];                     // 4096 B
  __shared__ int idxs[MTILE];                     // 2048 B
  __shared__ float redbuf[8];

  const int tid = threadIdx.x;
  const int wave = tid >> 6;
  const int lane = tid & 63;
  const int quad = lane >> 4;
  const int col = lane & 15;
  const long blockRow0 = (long)blockIdx.x * MTILE;
  const int waveRow0 = wave * 64;

  // ---- Stage padded bf16 codebook (139264 B = 8704 x 16B chunks) via
  // global_load_lds: wave-uniform LDS base + lane*16, per-lane global src.
  // 8704 chunks / 512 threads = exactly 17 iterations.
  const char* gbase = (const char*)cbb;
#pragma unroll
  for (int i = 0; i < 17; ++i) {
    const int chunk0 = i * NTH + wave * 64;  // wave-uniform
    const char* src = gbase + (size_t)(chunk0 + lane) * 16;
    __builtin_amdgcn_global_load_lds(
        (const __attribute__((address_space(1))) void*)src,
        (__attribute__((address_space(3))) void*)(cbs + (size_t)chunk0 * 8),
        16, 0, 0);
  }
  c2s[tid] = c2b[tid];
  c2s[tid + 512] = c2b[tid + 512];

  // ---- A fragments: bf16(-2*x). A[m=lane&15][k=quad*8+j], rows mi*16+col.
  // Issued while the global_load_lds queue drains (independent).
  short8 Af[4][2];
#pragma unroll
  for (int mi = 0; mi < 4; ++mi) {
#pragma unroll
    for (int ks = 0; ks < 2; ++ks) {
      long row = blockRow0 + waveRow0 + mi * 16 + col;
      const f32x4* xp = (const f32x4*)(x + row * VQ_D + ks * 32 + quad * 8);
      f32x4 lo = xp[0];
      f32x4 hi = xp[1];
      short8 a;
      a[0] = (short)f2bf(-2.f * lo[0]); a[1] = (short)f2bf(-2.f * lo[1]);
      a[2] = (short)f2bf(-2.f * lo[2]); a[3] = (short)f2bf(-2.f * lo[3]);
      a[4] = (short)f2bf(-2.f * hi[0]); a[5] = (short)f2bf(-2.f * hi[1]);
      a[6] = (short)f2bf(-2.f * hi[2]); a[7] = (short)f2bf(-2.f * hi[3]);
      Af[mi][ks] = a;
    }
  }

  unsigned bk[4][4];
#pragma unroll
  for (int mi = 0; mi < 4; ++mi)
#pragma unroll
    for (int r = 0; r < 4; ++r) bk[mi][r] = 0xFFFFFFFFu;

  __syncthreads();  // codebook staged (vmcnt drained by barrier); only barrier before epilogue

  // ---- Barrier-free K-loop: 64 iters x 16 codes. LDS + MFMA + VALU only.
  const unsigned short* bbase = cbs + (size_t)col * CSTRIDE + quad * 8;
#pragma unroll 4
  for (int t = 0; t < 64; ++t) {
    const unsigned short* bp = bbase + t * 16 * CSTRIDE;
    short8 b0 = *(const short8*)bp;
    short8 b1 = *(const short8*)(bp + 32);
    float cc = c2s[t * 16 + col];

    f32x4 acc[4];
#pragma unroll
    for (int mi = 0; mi < 4; ++mi) {
      f32x4 a = {cc, cc, cc, cc};
      a = __builtin_amdgcn_mfma_f32_16x16x32_bf16(Af[mi][0], b0, a, 0, 0, 0);
      a = __builtin_amdgcn_mfma_f32_16x16x32_bf16(Af[mi][1], b1, a, 0, 0, 0);
      acc[mi] = a;
    }

    const unsigned code = (unsigned)((t << 4) + col);
#pragma unroll
    for (int mi = 0; mi < 4; ++mi)
#pragma unroll
      for (int r = 0; r < 4; ++r)
        bk[mi][r] = min(bk[mi][r], (__float_as_uint(acc[mi][r]) & 0xFFFFFC00u) | code);
  }

  // ---- Reduce keys across the 16 columns of each quad group.
#pragma unroll
  for (int off = 1; off < 16; off <<= 1) {
#pragma unroll
    for (int mi = 0; mi < 4; ++mi)
#pragma unroll
      for (int r = 0; r < 4; ++r) {
        unsigned o = (unsigned)__shfl_xor((int)bk[mi][r], off);
        bk[mi][r] = min(bk[mi][r], o);
      }
  }
  if (col == 0) {
#pragma unroll
    for (int mi = 0; mi < 4; ++mi)
#pragma unroll
      for (int r = 0; r < 4; ++r)
        idxs[waveRow0 + mi * 16 + quad * 4 + r] = (int)(bk[mi][r] & 1023u);
  }
  __syncthreads();

  // ---- Epilogue: gather quantized rows from the LDS bf16 codebook (no global
  // gather), load x once for SSE, store out. 2 VMEM + 1 ds_read_b64 per iter.
  float sse = 0.f;
  const f32x4* x4 = (const f32x4*)x;
  f32x4* out4 = (f32x4*)out;
#pragma unroll
  for (int i = 0; i < 16; ++i) {
    int f = i * NTH + tid;  // float4 index within the 512x16 tile
    int row_l = f >> 4;
    int d4 = f & 15;
    int idx = idxs[row_l];
    unsigned long long ev =
        *(const unsigned long long*)(cbs + (size_t)idx * CSTRIDE + d4 * 4);
    f32x4 cv;
    cv[0] = __uint_as_float((unsigned)(ev & 0xFFFFull) << 16);
    cv[1] = __uint_as_float((unsigned)((ev >> 16) & 0xFFFFull) << 16);
    cv[2] = __uint_as_float((unsigned)((ev >> 32) & 0xFFFFull) << 16);
    cv[3] = __uint_as_float((unsigned)((ev >> 48) & 0xFFFFull) << 16);
    long gi = (blockRow0 + row_l) * 16 + d4;
    f32x4 xv = x4[gi];
    out4[gi] = cv;
    f32x4 dv = cv - xv;
    sse += dv[0] * dv[0] + dv[1] * dv[1] + dv[2] * dv[2] + dv[3] * dv[3];
  }
#pragma unroll
  for (int off = 32; off; off >>= 1) sse += __shfl_down(sse, off);
  if (lane == 0) redbuf[wave] = sse;
  __syncthreads();

  if (tid == 0) {
    float s = 0.f;
#pragma unroll
    for (int w = 0; w < 8; ++w) s += redbuf[w];
    atomicAdd(sse_out, s);
    __threadfence();
    unsigned old = atomicAdd(counter, 1u);
    if (old == (unsigned)(nblocks - 1)) {
      float tot = atomicAdd(sse_out, 0.f);
      long nelem = (long)nblocks * MTILE * VQ_D;
      out[nelem] = 1.25f * tot / (float)nelem;
    }
  }
}

extern "C" void kernel_launch(void* const* d_in, const int* in_sizes, int n_in,
                              void* d_out, int out_size, void* d_ws, size_t ws_size,
                              hipStream_t stream) {
  const float* x = (const float*)d_in[0];
  const float* cb = (const float*)d_in[1];
  float* out = (float*)d_out;

  const long n_elem = (long)in_sizes[0];   // 8388608
  const int nrows = (int)(n_elem / VQ_D);  // 131072
  const int K = in_sizes[1] / VQ_D;        // 1024
  const int nblocks = nrows / MTILE;       // 256

  char* ws = (char*)d_ws;
  float* sse = (float*)ws;                             // 4 B
  unsigned* counter = (unsigned*)(ws + 64);            // 4 B
  float* c2b = (float*)(ws + 256);                     // 4 KB
  unsigned short* cbb = (unsigned short*)(ws + 8192);  // 139264 B padded bf16 codebook

  vq_prep<<<dim3((K * 64 + 255) / 256), dim3(256), 0, stream>>>(cb, c2b, cbb, sse, counter, K);
  vq_main<<<dim3(nblocks), dim3(NTH), 0, stream>>>(x, cb, c2b, cbb, out, sse, counter, nblocks);
}

// Round 6
// 129.020 us; speedup vs baseline: 1.9980x; 1.0245x over previous
//
#include <hip/hip_runtime.h>

// VectorQuantizer gfx950 R10: phase-split for attribution + epilogue elimination.
// R4..R9 ledger: five different structures all 57-66 us (MfmaUtil~10, VALU~20,
// HBM~1TB/s) => ~73% unattributed stall. R10 splits vq_main into separately
// rocprof-timed dispatches AND removes the x re-read:
//  - vq_argmin (256x512, 1 block/CU): stage padded bf16 codebook via
//    global_load_lds, A-frags bf16(-2x) + fp32 row norms, barrier-free 64-iter
//    MFMA K-loop, packed-key argmin. NEW: SSE computed here from the packed key
//    (s_rec = bits&~1023, err<=6e-5 -> loss err ~1e-6) + fp32 ||x||^2, so the
//    32 MB output write and x re-read leave this kernel. Writes 512 indices.
//  - vq_gather (2048x256, no LDS, full occupancy): out rows = exact fp32
//    codebook gather (L2-resident 256 KB), coalesced 32 MB write. Pure
//    streaming; R7 proved this grid shape sustains 3.3+ TB/s.
// dist2[n,k] = ||x||^2 - 2 x.e_k + ||e_k||^2 ; argmin invariant to ||x||^2.
// MFMA C-init cc = 0.5 + ||e_k||^2 => s in [0.375,0.625] (>0 => IEEE bits
// order-monotonic). key = (bits(s) & ~1023) | code; argmin = v_min_u32.
// dist2_min = s_min - 0.5 + ||x||^2 (fp32 norms from staging registers).

typedef __attribute__((ext_vector_type(8))) short short8;
typedef __attribute__((ext_vector_type(4))) float f32x4;

#define VQ_D 64
#define MTILE 512   // rows per block (8 waves x 64 rows)
#define NTH 512
#define CSTRIDE 68  // ushorts per code row (64 data + 4 pad), padded in GLOBAL too

__device__ inline unsigned short f2bf(float f) {
  union { float f; unsigned u; } v; v.f = f;
  unsigned r = v.u + 0x7FFFu + ((v.u >> 16) & 1u);  // RNE
  return (unsigned short)(r >> 16);
}

// Prep: one wave per codebook row. c2b[k] = 0.5 + ||e_k||^2 ; codebook -> bf16
// in the PADDED stride-68 layout (zeroed pad) so vq_argmin can do a linear
// global_load_lds copy. Also zeroes the sse accumulator and completion counter.
__global__ __launch_bounds__(256) void vq_prep(const float* __restrict__ cb,
                                               float* __restrict__ c2b,
                                               unsigned short* __restrict__ cbb,
                                               float* __restrict__ sse,
                                               unsigned* __restrict__ counter, int K) {
  if (blockIdx.x == 0 && threadIdx.x == 0) { *sse = 0.f; *counter = 0u; }
  int w = (int)((blockIdx.x * 256 + threadIdx.x) >> 6);
  int lane = threadIdx.x & 63;
  if (w >= K) return;
  float v = cb[(size_t)w * VQ_D + lane];
  cbb[(size_t)w * CSTRIDE + lane] = f2bf(v);
  if (lane < CSTRIDE - VQ_D) cbb[(size_t)w * CSTRIDE + VQ_D + lane] = 0;
  float s = v * v;
#pragma unroll
  for (int off = 32; off; off >>= 1) s += __shfl_down(s, off);
  if (lane == 0) c2b[w] = s + 0.5f;
}

__global__ __launch_bounds__(NTH) void vq_argmin(
    const float* __restrict__ x, const float* __restrict__ c2b,
    const unsigned short* __restrict__ cbb, int* __restrict__ gidx,
    float* __restrict__ out, float* __restrict__ sse_out,
    unsigned* __restrict__ counter, int nblocks) {
  __shared__ unsigned short cbs[1024 * CSTRIDE];  // 139264 B
  __shared__ float c2s[1024];                     // 4096 B
  __shared__ int idxs[MTILE];                     // 2048 B
  __shared__ float xn[MTILE];                     // 2048 B fp32 ||x||^2 per row
  __shared__ float redbuf[8];

  const int tid = threadIdx.x;
  const int wave = tid >> 6;
  const int lane = tid & 63;
  const int quad = lane >> 4;
  const int col = lane & 15;
  const long blockRow0 = (long)blockIdx.x * MTILE;
  const int waveRow0 = wave * 64;

  // ---- Stage padded bf16 codebook (139264 B = 8704 x 16B chunks) via
  // global_load_lds: wave-uniform LDS base + lane*16, per-lane global src.
  const char* gbase = (const char*)cbb;
#pragma unroll
  for (int i = 0; i < 17; ++i) {
    const int chunk0 = i * NTH + wave * 64;  // wave-uniform
    const char* src = gbase + (size_t)(chunk0 + lane) * 16;
    __builtin_amdgcn_global_load_lds(
        (const __attribute__((address_space(1))) void*)src,
        (__attribute__((address_space(3))) void*)(cbs + (size_t)chunk0 * 8),
        16, 0, 0);
  }
  c2s[tid] = c2b[tid];
  c2s[tid + 512] = c2b[tid + 512];

  // ---- A fragments: bf16(-2*x) + fp32 row norms. Lane(quad,col) holds dims
  // [ks*32+quad*8,+8) of row mi*16+col; norm partial = 16 dims, quad-reduced.
  short8 Af[4][2];
#pragma unroll
  for (int mi = 0; mi < 4; ++mi) {
    float nrm = 0.f;
#pragma unroll
    for (int ks = 0; ks < 2; ++ks) {
      long row = blockRow0 + waveRow0 + mi * 16 + col;
      const f32x4* xp = (const f32x4*)(x + row * VQ_D + ks * 32 + quad * 8);
      f32x4 lo = xp[0];
      f32x4 hi = xp[1];
      nrm += lo[0] * lo[0] + lo[1] * lo[1] + lo[2] * lo[2] + lo[3] * lo[3];
      nrm += hi[0] * hi[0] + hi[1] * hi[1] + hi[2] * hi[2] + hi[3] * hi[3];
      short8 a;
      a[0] = (short)f2bf(-2.f * lo[0]); a[1] = (short)f2bf(-2.f * lo[1]);
      a[2] = (short)f2bf(-2.f * lo[2]); a[3] = (short)f2bf(-2.f * lo[3]);
      a[4] = (short)f2bf(-2.f * hi[0]); a[5] = (short)f2bf(-2.f * hi[1]);
      a[6] = (short)f2bf(-2.f * hi[2]); a[7] = (short)f2bf(-2.f * hi[3]);
      Af[mi][ks] = a;
    }
    nrm += __shfl_xor(nrm, 16);  // sum across the 4 quads (full 64-dim norm)
    nrm += __shfl_xor(nrm, 32);
    if (quad == 0) xn[waveRow0 + mi * 16 + col] = nrm;
  }

  unsigned bk[4][4];
#pragma unroll
  for (int mi = 0; mi < 4; ++mi)
#pragma unroll
    for (int r = 0; r < 4; ++r) bk[mi][r] = 0xFFFFFFFFu;

  __syncthreads();  // codebook staged (vmcnt drained), xn visible

  // ---- Barrier-free K-loop: 64 iters x 16 codes. LDS + MFMA + VALU only.
  const unsigned short* bbase = cbs + (size_t)col * CSTRIDE + quad * 8;
#pragma unroll 4
  for (int t = 0; t < 64; ++t) {
    const unsigned short* bp = bbase + t * 16 * CSTRIDE;
    short8 b0 = *(const short8*)bp;
    short8 b1 = *(const short8*)(bp + 32);
    float cc = c2s[t * 16 + col];

    f32x4 acc[4];
#pragma unroll
    for (int mi = 0; mi < 4; ++mi) {
      f32x4 a = {cc, cc, cc, cc};
      a = __builtin_amdgcn_mfma_f32_16x16x32_bf16(Af[mi][0], b0, a, 0, 0, 0);
      a = __builtin_amdgcn_mfma_f32_16x16x32_bf16(Af[mi][1], b1, a, 0, 0, 0);
      acc[mi] = a;
    }

    const unsigned code = (unsigned)((t << 4) + col);
#pragma unroll
    for (int mi = 0; mi < 4; ++mi)
#pragma unroll
      for (int r = 0; r < 4; ++r)
        bk[mi][r] = min(bk[mi][r], (__float_as_uint(acc[mi][r]) & 0xFFFFFC00u) | code);
  }

  // ---- Reduce keys across the 16 columns of each quad group.
#pragma unroll
  for (int off = 1; off < 16; off <<= 1) {
#pragma unroll
    for (int mi = 0; mi < 4; ++mi)
#pragma unroll
      for (int r = 0; r < 4; ++r) {
        unsigned o = (unsigned)__shfl_xor((int)bk[mi][r], off);
        bk[mi][r] = min(bk[mi][r], o);
      }
  }

  // ---- Indices + SSE from the packed keys (no output pass, no x re-read).
  // Row of bk[mi][r] at this quad = waveRow0 + mi*16 + quad*4 + r.
  float sse = 0.f;
  if (col == 0) {
#pragma unroll
    for (int mi = 0; mi < 4; ++mi)
#pragma unroll
      for (int r = 0; r < 4; ++r) {
        const int row = waveRow0 + mi * 16 + quad * 4 + r;
        idxs[row] = (int)(bk[mi][r] & 1023u);
        const float s_rec = __uint_as_float(bk[mi][r] & 0xFFFFFC00u);
        sse += s_rec - 0.5f + xn[row];
      }
  }
  sse += __shfl_xor(sse, 16);  // sum the 4 quads' col==0 lanes
  sse += __shfl_xor(sse, 32);
  if (lane == 0) redbuf[wave] = sse;
  __syncthreads();

  gidx[blockRow0 + tid] = idxs[tid];  // coalesced 2 KB index write (MTILE==NTH)

  if (tid == 0) {
    float s = 0.f;
#pragma unroll
    for (int w = 0; w < 8; ++w) s += redbuf[w];
    atomicAdd(sse_out, s);
    __threadfence();
    unsigned old = atomicAdd(counter, 1u);
    if (old == (unsigned)(nblocks - 1)) {
      float tot = atomicAdd(sse_out, 0.f);
      long nelem = (long)nblocks * MTILE * VQ_D;
      out[nelem] = 1.25f * tot / (float)nelem;
    }
  }
}

// Pure streaming scatter: out row = exact fp32 codebook row. Full occupancy,
// no LDS; 16 consecutive threads share one idx (L1 broadcast); cb is 256 KB
// L2/L3-resident; 32 MB coalesced write.
__global__ __launch_bounds__(256) void vq_gather(const float* __restrict__ cb,
                                                 const int* __restrict__ gidx,
                                                 float* __restrict__ out) {
  const int t = blockIdx.x * 256 + threadIdx.x;  // 2^19 threads
  const f32x4* cb4 = (const f32x4*)cb;
  f32x4* out4 = (f32x4*)out;
#pragma unroll
  for (int i = 0; i < 4; ++i) {
    const int f = t + i * (1 << 19);  // 2^21 float4s total
    const int row = f >> 4;
    const int d4 = f & 15;
    out4[f] = cb4[(size_t)gidx[row] * 16 + d4];
  }
}

extern "C" void kernel_launch(void* const* d_in, const int* in_sizes, int n_in,
                              void* d_out, int out_size, void* d_ws, size_t ws_size,
                              hipStream_t stream) {
  const float* x = (const float*)d_in[0];
  const float* cb = (const float*)d_in[1];
  float* out = (float*)d_out;

  const long n_elem = (long)in_sizes[0];   // 8388608
  const int nrows = (int)(n_elem / VQ_D);  // 131072
  const int K = in_sizes[1] / VQ_D;        // 1024
  const int nblocks = nrows / MTILE;       // 256

  char* ws = (char*)d_ws;
  float* sse = (float*)ws;                             // 4 B
  unsigned* counter = (unsigned*)(ws + 64);            // 4 B
  float* c2b = (float*)(ws + 256);                     // 4 KB
  unsigned short* cbb = (unsigned short*)(ws + 8192);  // 139264 B padded bf16 codebook
  int* gidx = (int*)(ws + 8192 + 139264);              // 512 KB row indices

  vq_prep<<<dim3((K * 64 + 255) / 256), dim3(256), 0, stream>>>(cb, c2b, cbb, sse, counter, K);
  vq_argmin<<<dim3(nblocks), dim3(NTH), 0, stream>>>(x, c2b, cbb, gidx, out, sse, counter, nblocks);
  vq_gather<<<dim3(nrows * 16 / (256 * 4)), dim3(256), 0, stream>>>(cb, gidx, out);
}